// Round 1
// baseline (661.953 us; speedup 1.0000x reference)
//
#include <hip/hip_runtime.h>
#include <hip/hip_bf16.h>

// Problem constants (B=4, C=256, H=W=64, groups=8, heads=4)
#define BB   4
#define CC   256
#define NN   4096      // H*W
#define NH   4
#define HD   64
#define NG   8
#define GSZ  32        // channels per group
#define EPSV 1e-5f
#define SCALE 0.125f   // 64^-0.5

typedef __bf16 bf16x8 __attribute__((ext_vector_type(8)));
typedef float  f32x4  __attribute__((ext_vector_type(4)));

#define MFMA16(a, b, c) __builtin_amdgcn_mfma_f32_16x16x32_bf16((a), (b), (c), 0, 0, 0)

__device__ inline unsigned short f2bf(float f) {
    unsigned int u = __float_as_uint(f);
    u += 0x7fffu + ((u >> 16) & 1u);   // RNE
    return (unsigned short)(u >> 16);
}

// ---------------- kernel 1: convert weights fp32 -> bf16 ----------------
__global__ void k_cvt(const float* __restrict__ wq, const float* __restrict__ wp,
                      unsigned short* __restrict__ oq, unsigned short* __restrict__ op) {
    int i = blockIdx.x * 256 + threadIdx.x;
    if (i < 3 * CC * CC) oq[i] = f2bf(wq[i]);
    if (i < CC * CC)     op[i] = f2bf(wp[i]);
}

// ---------------- kernel 2: groupnorm stats (sum, sumsq) ----------------
// grid = B*NG*8 splits, 256 threads. Group data is contiguous: 32ch x 4096.
__global__ void k_gnstats(const float* __restrict__ x, float* __restrict__ stats) {
    int blk = blockIdx.x;
    int b = blk >> 6, g = (blk >> 3) & 7, s = blk & 7;
    const float* p = x + ((size_t)(b * CC + g * GSZ)) * NN + s * 16384;
    int t = threadIdx.x;
    float s0 = 0.f, s1 = 0.f;
    #pragma unroll
    for (int i = 0; i < 64; ++i) { float v = p[i * 256 + t]; s0 += v; s1 += v * v; }
    #pragma unroll
    for (int m = 1; m <= 32; m <<= 1) { s0 += __shfl_xor(s0, m); s1 += __shfl_xor(s1, m); }
    __shared__ float ls[8];
    int w = t >> 6;
    if ((t & 63) == 0) { ls[w * 2] = s0; ls[w * 2 + 1] = s1; }
    __syncthreads();
    if (t == 0) {
        float a0 = ls[0] + ls[2] + ls[4] + ls[6];
        float a1 = ls[1] + ls[3] + ls[5] + ls[7];
        atomicAdd(&stats[(b * NG + g) * 2 + 0], a0);
        atomicAdd(&stats[(b * NG + g) * 2 + 1], a1);
    }
}

// ------- kernel 3: groupnorm apply + transpose -> ht[b][n][c] (bf16) -------
// grid (64 n-tiles, 8 c-tiles, B); tile = 64n x 32c via LDS.
__global__ void k_gnapply(const float* __restrict__ x, const float* __restrict__ gw,
                          const float* __restrict__ gb, const float* __restrict__ stats,
                          unsigned short* __restrict__ ht) {
    int b = blockIdx.z, ct = blockIdx.y, nt = blockIdx.x;
    int c0 = ct * 32, n0 = nt * 64;
    int t = threadIdx.x;
    __shared__ float tile[32][65];
    const float* xp = x + ((size_t)(b * CC + c0)) * NN + n0;
    int cl = t >> 6, nl = t & 63;
    #pragma unroll
    for (int p = 0; p < 8; ++p)
        tile[p * 4 + cl][nl] = xp[(size_t)(p * 4 + cl) * NN + nl];
    float sum = stats[(b * NG + ct) * 2 + 0];
    float ssq = stats[(b * NG + ct) * 2 + 1];
    float mean = sum * (1.0f / 131072.0f);
    float var  = ssq * (1.0f / 131072.0f) - mean * mean;
    float inv  = rsqrtf(var + EPSV);
    __syncthreads();
    int nw = t >> 2, ci = (t & 3) * 8;
    alignas(16) unsigned short o8[8];
    #pragma unroll
    for (int j = 0; j < 8; ++j) {
        int c = c0 + ci + j;
        float v = (tile[ci + j][nw] - mean) * inv * gw[c] + gb[c];
        o8[j] = f2bf(v);
    }
    *reinterpret_cast<uint4*>(ht + ((size_t)(b * NN + n0 + nw)) * CC + c0 + ci) =
        *reinterpret_cast<const uint4*>(o8);
}

// ---------------- kernel 4: QKV GEMM (bf16 MFMA) ----------------
// qkv[o][n] = sum_c W[o][c] * h[c][n] + bias.  o = s*256 + h*64 + d.
// q,k stored [bh][n][d] (scale folded into q); v stored [bh][d][n].
__global__ void k_qkv(const unsigned short* __restrict__ ht, const unsigned short* __restrict__ wq,
                      const float* __restrict__ qb,
                      unsigned short* __restrict__ qt, unsigned short* __restrict__ kt,
                      unsigned short* __restrict__ vt) {
    int b = blockIdx.z, by = blockIdx.y, bx = blockIdx.x;
    int t = threadIdx.x, wave = t >> 6, lane = t & 63;
    int l15 = lane & 15, quad = lane >> 4;
    int o0 = by * 16;
    int n = bx * 64 + wave * 16 + l15;
    const unsigned short* ap = wq + (size_t)(o0 + l15) * CC + quad * 8;
    const unsigned short* bp = ht + ((size_t)(b * NN + n)) * CC + quad * 8;
    f32x4 acc = {0.f, 0.f, 0.f, 0.f};
    #pragma unroll
    for (int kk = 0; kk < 8; ++kk) {
        bf16x8 a  = *reinterpret_cast<const bf16x8*>(ap + kk * 32);
        bf16x8 bb = *reinterpret_cast<const bf16x8*>(bp + kk * 32);
        acc = MFMA16(a, bb, acc);
    }
    int s = by >> 4, h = (by >> 2) & 3, d0 = (by & 3) * 16 + quad * 4;
    int orow = o0 + quad * 4;
    if (s == 0) {
        alignas(8) unsigned short o4[4];
        #pragma unroll
        for (int r = 0; r < 4; ++r) o4[r] = f2bf((acc[r] + qb[orow + r]) * SCALE);
        *reinterpret_cast<uint2*>(qt + (((size_t)(b * NH + h) * NN) + n) * HD + d0) =
            *reinterpret_cast<const uint2*>(o4);
    } else if (s == 1) {
        alignas(8) unsigned short o4[4];
        #pragma unroll
        for (int r = 0; r < 4; ++r) o4[r] = f2bf(acc[r] + qb[orow + r]);
        *reinterpret_cast<uint2*>(kt + (((size_t)(b * NH + h) * NN) + n) * HD + d0) =
            *reinterpret_cast<const uint2*>(o4);
    } else {
        #pragma unroll
        for (int r = 0; r < 4; ++r)
            vt[(((size_t)(b * NH + h) * HD) + d0 + r) * NN + n] = f2bf(acc[r] + qb[orow + r]);
    }
}

// ---------------- kernel 5: flash attention (bf16 MFMA) ----------------
// grid (64 q-tiles, B*NH); block 256 = 4 waves; wave owns 16 queries.
__global__ void k_attn(const unsigned short* __restrict__ qt, const unsigned short* __restrict__ kt,
                       const unsigned short* __restrict__ vt, unsigned short* __restrict__ ao) {
    int bh = blockIdx.y;
    int t = threadIdx.x, wave = t >> 6, lane = t & 63;
    int l15 = lane & 15, quad = lane >> 4;
    int qbase = blockIdx.x * 64 + wave * 16;
    const unsigned short* qp = qt + (size_t)bh * NN * HD;
    const unsigned short* kp = kt + (size_t)bh * NN * HD;
    const unsigned short* vp = vt + (size_t)bh * HD * NN;

    bf16x8 qa0 = *reinterpret_cast<const bf16x8*>(qp + (size_t)(qbase + l15) * HD + quad * 8);
    bf16x8 qa1 = *reinterpret_cast<const bf16x8*>(qp + (size_t)(qbase + l15) * HD + 32 + quad * 8);

    f32x4 O[4];
    float mi[4], li[4];
    #pragma unroll
    for (int i = 0; i < 4; ++i) { O[i] = (f32x4){0.f, 0.f, 0.f, 0.f}; mi[i] = -1e30f; li[i] = 0.f; }

    __shared__ alignas(16) unsigned short plds[4][512];   // per-wave 16x32 P tile
    unsigned short* pw = plds[wave];

    for (int mt = 0; mt < 128; ++mt) {
        int m0 = mt * 32;
        f32x4 s0 = {0.f, 0.f, 0.f, 0.f}, s1 = {0.f, 0.f, 0.f, 0.f};
        bf16x8 k00 = *reinterpret_cast<const bf16x8*>(kp + (size_t)(m0 + l15) * HD + quad * 8);
        bf16x8 k01 = *reinterpret_cast<const bf16x8*>(kp + (size_t)(m0 + l15) * HD + 32 + quad * 8);
        s0 = MFMA16(qa0, k00, s0);
        s0 = MFMA16(qa1, k01, s0);
        bf16x8 k10 = *reinterpret_cast<const bf16x8*>(kp + (size_t)(m0 + 16 + l15) * HD + quad * 8);
        bf16x8 k11 = *reinterpret_cast<const bf16x8*>(kp + (size_t)(m0 + 16 + l15) * HD + 32 + quad * 8);
        s1 = MFMA16(qa0, k10, s1);
        s1 = MFMA16(qa1, k11, s1);

        #pragma unroll
        for (int r = 0; r < 4; ++r) {
            float mx = fmaxf(s0[r], s1[r]);
            #pragma unroll
            for (int ofs = 1; ofs < 16; ofs <<= 1) mx = fmaxf(mx, __shfl_xor(mx, ofs));
            float mn = fmaxf(mi[r], mx);
            float al = __expf(mi[r] - mn);
            float p0 = __expf(s0[r] - mn);
            float p1 = __expf(s1[r] - mn);
            float rs = p0 + p1;
            #pragma unroll
            for (int ofs = 1; ofs < 16; ofs <<= 1) rs += __shfl_xor(rs, ofs);
            li[r] = li[r] * al + rs;
            mi[r] = mn;
            O[0][r] *= al; O[1][r] *= al; O[2][r] *= al; O[3][r] *= al;
            pw[(quad * 4 + r) * 32 + l15]      = f2bf(p0);
            pw[(quad * 4 + r) * 32 + 16 + l15] = f2bf(p1);
        }
        __syncthreads();   // order P writes before A-fragment reads (per-wave region)
        bf16x8 pa = *reinterpret_cast<const bf16x8*>(pw + l15 * 32 + quad * 8);
        #pragma unroll
        for (int dc = 0; dc < 4; ++dc) {
            bf16x8 vb = *reinterpret_cast<const bf16x8*>(vp + (size_t)(dc * 16 + l15) * NN + m0 + quad * 8);
            O[dc] = MFMA16(pa, vb, O[dc]);
        }
    }

    int b = bh >> 2, h = bh & 3;
    #pragma unroll
    for (int dc = 0; dc < 4; ++dc) {
        #pragma unroll
        for (int r = 0; r < 4; ++r) {
            int nrow = qbase + quad * 4 + r;
            ao[((size_t)(b * NN) + nrow) * CC + h * HD + dc * 16 + l15] = f2bf(O[dc][r] / li[r]);
        }
    }
}

// ---------------- kernel 6: proj GEMM + bias + residual (fp32 out) ----------------
__global__ void k_proj(const unsigned short* __restrict__ ao, const unsigned short* __restrict__ wp,
                       const float* __restrict__ pb, const float* __restrict__ x,
                       float* __restrict__ out) {
    int b = blockIdx.z, by = blockIdx.y, bx = blockIdx.x;
    int t = threadIdx.x, wave = t >> 6, lane = t & 63;
    int l15 = lane & 15, quad = lane >> 4;
    int o0 = by * 16;
    int n = bx * 64 + wave * 16 + l15;
    const unsigned short* ap = wp + (size_t)(o0 + l15) * CC + quad * 8;
    const unsigned short* bp = ao + ((size_t)(b * NN + n)) * CC + quad * 8;
    f32x4 acc = {0.f, 0.f, 0.f, 0.f};
    #pragma unroll
    for (int kk = 0; kk < 8; ++kk) {
        bf16x8 a  = *reinterpret_cast<const bf16x8*>(ap + kk * 32);
        bf16x8 bb = *reinterpret_cast<const bf16x8*>(bp + kk * 32);
        acc = MFMA16(a, bb, acc);
    }
    #pragma unroll
    for (int r = 0; r < 4; ++r) {
        int o = o0 + quad * 4 + r;
        size_t idx = ((size_t)(b * CC + o)) * NN + n;
        out[idx] = acc[r] + pb[o] + x[idx];
    }
}

extern "C" void kernel_launch(void* const* d_in, const int* in_sizes, int n_in,
                              void* d_out, int out_size, void* d_ws, size_t ws_size,
                              hipStream_t stream) {
    const float* x     = (const float*)d_in[0];
    const float* gw    = (const float*)d_in[1];
    const float* gb    = (const float*)d_in[2];
    const float* qkvw  = (const float*)d_in[3];
    const float* qkvb  = (const float*)d_in[4];
    const float* projw = (const float*)d_in[5];
    const float* projb = (const float*)d_in[6];
    float* out = (float*)d_out;

    char* w = (char*)d_ws;
    size_t off = 0;
    unsigned short* ht = (unsigned short*)(w + off); off += (size_t)BB * NN * CC * 2;       // 8 MB
    unsigned short* qt = (unsigned short*)(w + off); off += (size_t)BB * NH * NN * HD * 2;  // 8 MB
    unsigned short* kt = (unsigned short*)(w + off); off += (size_t)BB * NH * NN * HD * 2;  // 8 MB
    unsigned short* vt = (unsigned short*)(w + off); off += (size_t)BB * NH * HD * NN * 2;  // 8 MB
    unsigned short* ao = (unsigned short*)(w + off); off += (size_t)BB * NN * CC * 2;       // 8 MB
    unsigned short* wqb = (unsigned short*)(w + off); off += (size_t)3 * CC * CC * 2;       // 384 KB
    unsigned short* wpb = (unsigned short*)(w + off); off += (size_t)CC * CC * 2;           // 128 KB
    float* stats = (float*)(w + off); off += BB * NG * 2 * sizeof(float);

    hipMemsetAsync(stats, 0, BB * NG * 2 * sizeof(float), stream);
    k_cvt<<<768, 256, 0, stream>>>(qkvw, projw, wqb, wpb);
    k_gnstats<<<BB * NG * 8, 256, 0, stream>>>(x, stats);
    k_gnapply<<<dim3(NN / 64, CC / 32, BB), 256, 0, stream>>>(x, gw, gb, stats, ht);
    k_qkv<<<dim3(NN / 64, 3 * CC / 16, BB), 256, 0, stream>>>(ht, wqb, qkvb, qt, kt, vt);
    k_attn<<<dim3(NN / 64, BB * NH), 256, 0, stream>>>(qt, kt, vt, ao);
    k_proj<<<dim3(NN / 64, CC / 16, BB), 256, 0, stream>>>(ao, wpb, projb, x, out);
}

// Round 2
// 661.063 us; speedup vs baseline: 1.0013x; 1.0013x over previous
//
#include <hip/hip_runtime.h>
#include <hip/hip_bf16.h>

// Problem constants (B=4, C=256, H=W=64, groups=8, heads=4)
#define BB   4
#define CC   256
#define NN   4096      // H*W
#define NH   4
#define HD   64
#define NG   8
#define GSZ  32        // channels per group
#define EPSV 1e-5f
#define SCALE 0.125f   // 64^-0.5

typedef __bf16 bf16x8 __attribute__((ext_vector_type(8)));
typedef float  f32x4  __attribute__((ext_vector_type(4)));

#define MFMA16(a, b, c) __builtin_amdgcn_mfma_f32_16x16x32_bf16((a), (b), (c), 0, 0, 0)

__device__ inline unsigned short f2bf(float f) {
    unsigned int u = __float_as_uint(f);
    u += 0x7fffu + ((u >> 16) & 1u);   // RNE
    return (unsigned short)(u >> 16);
}

// ---------------- kernel 1: convert weights fp32 -> bf16 ----------------
__global__ void k_cvt(const float* __restrict__ wq, const float* __restrict__ wp,
                      unsigned short* __restrict__ oq, unsigned short* __restrict__ op) {
    int i = blockIdx.x * 256 + threadIdx.x;
    if (i < 3 * CC * CC) oq[i] = f2bf(wq[i]);
    if (i < CC * CC)     op[i] = f2bf(wp[i]);
}

// ---------------- kernel 2: groupnorm stats (sum, sumsq) ----------------
__global__ void k_gnstats(const float* __restrict__ x, float* __restrict__ stats) {
    int blk = blockIdx.x;
    int b = blk >> 6, g = (blk >> 3) & 7, s = blk & 7;
    const float* p = x + ((size_t)(b * CC + g * GSZ)) * NN + s * 16384;
    int t = threadIdx.x;
    float s0 = 0.f, s1 = 0.f;
    #pragma unroll
    for (int i = 0; i < 64; ++i) { float v = p[i * 256 + t]; s0 += v; s1 += v * v; }
    #pragma unroll
    for (int m = 1; m <= 32; m <<= 1) { s0 += __shfl_xor(s0, m); s1 += __shfl_xor(s1, m); }
    __shared__ float ls[8];
    int w = t >> 6;
    if ((t & 63) == 0) { ls[w * 2] = s0; ls[w * 2 + 1] = s1; }
    __syncthreads();
    if (t == 0) {
        float a0 = ls[0] + ls[2] + ls[4] + ls[6];
        float a1 = ls[1] + ls[3] + ls[5] + ls[7];
        atomicAdd(&stats[(b * NG + g) * 2 + 0], a0);
        atomicAdd(&stats[(b * NG + g) * 2 + 1], a1);
    }
}

// ------- kernel 3: groupnorm apply + transpose -> ht[b][n][c] (bf16) -------
__global__ void k_gnapply(const float* __restrict__ x, const float* __restrict__ gw,
                          const float* __restrict__ gb, const float* __restrict__ stats,
                          unsigned short* __restrict__ ht) {
    int b = blockIdx.z, ct = blockIdx.y, nt = blockIdx.x;
    int c0 = ct * 32, n0 = nt * 64;
    int t = threadIdx.x;
    __shared__ float tile[32][65];
    const float* xp = x + ((size_t)(b * CC + c0)) * NN + n0;
    int cl = t >> 6, nl = t & 63;
    #pragma unroll
    for (int p = 0; p < 8; ++p)
        tile[p * 4 + cl][nl] = xp[(size_t)(p * 4 + cl) * NN + nl];
    float sum = stats[(b * NG + ct) * 2 + 0];
    float ssq = stats[(b * NG + ct) * 2 + 1];
    float mean = sum * (1.0f / 131072.0f);
    float var  = ssq * (1.0f / 131072.0f) - mean * mean;
    float inv  = rsqrtf(var + EPSV);
    __syncthreads();
    int nw = t >> 2, ci = (t & 3) * 8;
    alignas(16) unsigned short o8[8];
    #pragma unroll
    for (int j = 0; j < 8; ++j) {
        int c = c0 + ci + j;
        float v = (tile[ci + j][nw] - mean) * inv * gw[c] + gb[c];
        o8[j] = f2bf(v);
    }
    *reinterpret_cast<uint4*>(ht + ((size_t)(b * NN + n0 + nw)) * CC + c0 + ci) =
        *reinterpret_cast<const uint4*>(o8);
}

// ---------------- kernel 4: QKV GEMM (bf16 MFMA) ----------------
__global__ void k_qkv(const unsigned short* __restrict__ ht, const unsigned short* __restrict__ wq,
                      const float* __restrict__ qb,
                      unsigned short* __restrict__ qt, unsigned short* __restrict__ kt,
                      unsigned short* __restrict__ vt) {
    int b = blockIdx.z, by = blockIdx.y, bx = blockIdx.x;
    int t = threadIdx.x, wave = t >> 6, lane = t & 63;
    int l15 = lane & 15, quad = lane >> 4;
    int o0 = by * 16;
    int n = bx * 64 + wave * 16 + l15;
    const unsigned short* ap = wq + (size_t)(o0 + l15) * CC + quad * 8;
    const unsigned short* bp = ht + ((size_t)(b * NN + n)) * CC + quad * 8;
    f32x4 acc = {0.f, 0.f, 0.f, 0.f};
    #pragma unroll
    for (int kk = 0; kk < 8; ++kk) {
        bf16x8 a  = *reinterpret_cast<const bf16x8*>(ap + kk * 32);
        bf16x8 bb = *reinterpret_cast<const bf16x8*>(bp + kk * 32);
        acc = MFMA16(a, bb, acc);
    }
    int s = by >> 4, h = (by >> 2) & 3, d0 = (by & 3) * 16 + quad * 4;
    int orow = o0 + quad * 4;
    if (s == 0) {
        alignas(8) unsigned short o4[4];
        #pragma unroll
        for (int r = 0; r < 4; ++r) o4[r] = f2bf((acc[r] + qb[orow + r]) * SCALE);
        *reinterpret_cast<uint2*>(qt + (((size_t)(b * NH + h) * NN) + n) * HD + d0) =
            *reinterpret_cast<const uint2*>(o4);
    } else if (s == 1) {
        alignas(8) unsigned short o4[4];
        #pragma unroll
        for (int r = 0; r < 4; ++r) o4[r] = f2bf(acc[r] + qb[orow + r]);
        *reinterpret_cast<uint2*>(kt + (((size_t)(b * NH + h) * NN) + n) * HD + d0) =
            *reinterpret_cast<const uint2*>(o4);
    } else {
        #pragma unroll
        for (int r = 0; r < 4; ++r)
            vt[(((size_t)(b * NH + h) * HD) + d0 + r) * NN + n] = f2bf(acc[r] + qb[orow + r]);
    }
}

// ---------------- kernel 5: flash-style attention, no-LDS, no-rescale ----------------
// grid (64 q-tiles, B*NH); block 256 = 4 waves; wave owns 16 queries.
// S^T = MFMA(K, Q) so P^T reaches the PV B-fragment via 8 independent shfl +
// 4 v_perm per 32 keys (no LDS round trip, no barriers). Unnormalized exp
// (scores bounded; clamp at 80 guards inf), per-lane partial li reduced once
// at the end. O^T = MFMA(V^T, P^T).
__global__ void k_attn(const unsigned short* __restrict__ qt, const unsigned short* __restrict__ kt,
                       const unsigned short* __restrict__ vt, unsigned short* __restrict__ ao) {
    int bh = blockIdx.y;
    int t = threadIdx.x, wave = t >> 6, lane = t & 63;
    int l15 = lane & 15, quad = lane >> 4;
    int qbase = blockIdx.x * 64 + wave * 16;
    const unsigned short* qp = qt + (size_t)bh * NN * HD;
    const unsigned short* kp = kt + (size_t)bh * NN * HD;
    const unsigned short* vp = vt + (size_t)bh * HD * NN;

    bf16x8 qa0 = *reinterpret_cast<const bf16x8*>(qp + (size_t)(qbase + l15) * HD + quad * 8);
    bf16x8 qa1 = *reinterpret_cast<const bf16x8*>(qp + (size_t)(qbase + l15) * HD + 32 + quad * 8);

    f32x4 O[4];
    #pragma unroll
    for (int i = 0; i < 4; ++i) O[i] = (f32x4){0.f, 0.f, 0.f, 0.f};
    float li = 0.f;

    int srcA = (quad & 1) * 32 + l15;   // source lane for B-frag elems j=0..3
    int srcB = srcA + 16;               // j=4..7
    unsigned int psel = (quad >= 2) ? 0x07060302u : 0x05040100u;  // v_perm: hi(p1) vs lo(p0)

    for (int mt = 0; mt < 128; ++mt) {
        int m0 = mt * 32;
        bf16x8 k00 = *reinterpret_cast<const bf16x8*>(kp + (size_t)(m0 + l15) * HD + quad * 8);
        bf16x8 k01 = *reinterpret_cast<const bf16x8*>(kp + (size_t)(m0 + l15) * HD + 32 + quad * 8);
        bf16x8 k10 = *reinterpret_cast<const bf16x8*>(kp + (size_t)(m0 + 16 + l15) * HD + quad * 8);
        bf16x8 k11 = *reinterpret_cast<const bf16x8*>(kp + (size_t)(m0 + 16 + l15) * HD + 32 + quad * 8);
        f32x4 s0 = {0.f, 0.f, 0.f, 0.f}, s1 = {0.f, 0.f, 0.f, 0.f};
        // S^T: row = key = m0 + quad*4 + r (+16 for s1), col = q = l15
        s0 = MFMA16(k00, qa0, s0);
        s0 = MFMA16(k01, qa1, s0);
        s1 = MFMA16(k10, qa0, s1);
        s1 = MFMA16(k11, qa1, s1);

        // p = exp(s); pack[r] = bf16(p0[r]) | bf16(p1[r])<<16; accumulate per-lane li
        unsigned int pack[4];
        float psum = 0.f;
        #pragma unroll
        for (int r = 0; r < 4; ++r) {
            float p0 = __expf(fminf(s0[r], 80.f));
            float p1 = __expf(fminf(s1[r], 80.f));
            psum += p0 + p1;
            pack[r] = ((__float_as_uint(p0) + 0x8000u) >> 16) |
                      ((__float_as_uint(p1) + 0x8000u) & 0xffff0000u);
        }
        li += psum;

        // redistribute to PV B-fragment layout: lane needs keys m0+quad*8+j, q=l15
        int a0 = __shfl((int)pack[0], srcA);
        int a1 = __shfl((int)pack[1], srcA);
        int a2 = __shfl((int)pack[2], srcA);
        int a3 = __shfl((int)pack[3], srcA);
        int b0 = __shfl((int)pack[0], srcB);
        int b1 = __shfl((int)pack[1], srcB);
        int b2 = __shfl((int)pack[2], srcB);
        int b3 = __shfl((int)pack[3], srcB);
        alignas(16) unsigned int w[4];
        w[0] = __builtin_amdgcn_perm((unsigned)a1, (unsigned)a0, psel);
        w[1] = __builtin_amdgcn_perm((unsigned)a3, (unsigned)a2, psel);
        w[2] = __builtin_amdgcn_perm((unsigned)b1, (unsigned)b0, psel);
        w[3] = __builtin_amdgcn_perm((unsigned)b3, (unsigned)b2, psel);
        bf16x8 pfrag = *reinterpret_cast<const bf16x8*>(w);

        #pragma unroll
        for (int dc = 0; dc < 4; ++dc) {
            bf16x8 vb = *reinterpret_cast<const bf16x8*>(vp + (size_t)(dc * 16 + l15) * NN + m0 + quad * 8);
            O[dc] = MFMA16(vb, pfrag, O[dc]);   // O^T[d][q]
        }
    }

    // reduce li across the 4 quads (each lane's partial covers its key subset; q = l15)
    li += __shfl_xor(li, 16);
    li += __shfl_xor(li, 32);
    float inv = 1.0f / li;

    int b = bh >> 2, h = bh & 3;
    int q = qbase + l15;
    #pragma unroll
    for (int dc = 0; dc < 4; ++dc) {
        alignas(8) unsigned short o4[4];
        #pragma unroll
        for (int r = 0; r < 4; ++r) o4[r] = f2bf(O[dc][r] * inv);
        *reinterpret_cast<uint2*>(ao + ((size_t)(b * NN) + q) * CC + h * HD + dc * 16 + quad * 4) =
            *reinterpret_cast<const uint2*>(o4);
    }
}

// ---------------- kernel 6: proj GEMM + bias + residual (fp32 out) ----------------
__global__ void k_proj(const unsigned short* __restrict__ ao, const unsigned short* __restrict__ wp,
                       const float* __restrict__ pb, const float* __restrict__ x,
                       float* __restrict__ out) {
    int b = blockIdx.z, by = blockIdx.y, bx = blockIdx.x;
    int t = threadIdx.x, wave = t >> 6, lane = t & 63;
    int l15 = lane & 15, quad = lane >> 4;
    int o0 = by * 16;
    int n = bx * 64 + wave * 16 + l15;
    const unsigned short* ap = wp + (size_t)(o0 + l15) * CC + quad * 8;
    const unsigned short* bp = ao + ((size_t)(b * NN + n)) * CC + quad * 8;
    f32x4 acc = {0.f, 0.f, 0.f, 0.f};
    #pragma unroll
    for (int kk = 0; kk < 8; ++kk) {
        bf16x8 a  = *reinterpret_cast<const bf16x8*>(ap + kk * 32);
        bf16x8 bb = *reinterpret_cast<const bf16x8*>(bp + kk * 32);
        acc = MFMA16(a, bb, acc);
    }
    #pragma unroll
    for (int r = 0; r < 4; ++r) {
        int o = o0 + quad * 4 + r;
        size_t idx = ((size_t)(b * CC + o)) * NN + n;
        out[idx] = acc[r] + pb[o] + x[idx];
    }
}

extern "C" void kernel_launch(void* const* d_in, const int* in_sizes, int n_in,
                              void* d_out, int out_size, void* d_ws, size_t ws_size,
                              hipStream_t stream) {
    const float* x     = (const float*)d_in[0];
    const float* gw    = (const float*)d_in[1];
    const float* gb    = (const float*)d_in[2];
    const float* qkvw  = (const float*)d_in[3];
    const float* qkvb  = (const float*)d_in[4];
    const float* projw = (const float*)d_in[5];
    const float* projb = (const float*)d_in[6];
    float* out = (float*)d_out;

    char* w = (char*)d_ws;
    size_t off = 0;
    unsigned short* ht = (unsigned short*)(w + off); off += (size_t)BB * NN * CC * 2;       // 8 MB
    unsigned short* qt = (unsigned short*)(w + off); off += (size_t)BB * NH * NN * HD * 2;  // 8 MB
    unsigned short* kt = (unsigned short*)(w + off); off += (size_t)BB * NH * NN * HD * 2;  // 8 MB
    unsigned short* vt = (unsigned short*)(w + off); off += (size_t)BB * NH * HD * NN * 2;  // 8 MB
    unsigned short* ao = (unsigned short*)(w + off); off += (size_t)BB * NN * CC * 2;       // 8 MB
    unsigned short* wqb = (unsigned short*)(w + off); off += (size_t)3 * CC * CC * 2;       // 384 KB
    unsigned short* wpb = (unsigned short*)(w + off); off += (size_t)CC * CC * 2;           // 128 KB
    float* stats = (float*)(w + off); off += BB * NG * 2 * sizeof(float);

    hipMemsetAsync(stats, 0, BB * NG * 2 * sizeof(float), stream);
    k_cvt<<<768, 256, 0, stream>>>(qkvw, projw, wqb, wpb);
    k_gnstats<<<BB * NG * 8, 256, 0, stream>>>(x, stats);
    k_gnapply<<<dim3(NN / 64, CC / 32, BB), 256, 0, stream>>>(x, gw, gb, stats, ht);
    k_qkv<<<dim3(NN / 64, 3 * CC / 16, BB), 256, 0, stream>>>(ht, wqb, qkvb, qt, kt, vt);
    k_attn<<<dim3(NN / 64, BB * NH), 256, 0, stream>>>(qt, kt, vt, ao);
    k_proj<<<dim3(NN / 64, CC / 16, BB), 256, 0, stream>>>(ao, wpb, projb, x, out);
}

// Round 3
// 348.546 us; speedup vs baseline: 1.8992x; 1.8966x over previous
//
#include <hip/hip_runtime.h>
#include <hip/hip_bf16.h>

// Problem constants (B=4, C=256, H=W=64, groups=8, heads=4)
#define BB   4
#define CC   256
#define NN   4096      // H*W
#define NH   4
#define HD   64
#define NG   8
#define GSZ  32        // channels per group
#define EPSV 1e-5f
#define SCALE 0.125f   // 64^-0.5

typedef __bf16 bf16x8 __attribute__((ext_vector_type(8)));
typedef float  f32x4  __attribute__((ext_vector_type(4)));

#define MFMA16(a, b, c) __builtin_amdgcn_mfma_f32_16x16x32_bf16((a), (b), (c), 0, 0, 0)

__device__ inline unsigned short f2bf(float f) {
    unsigned int u = __float_as_uint(f);
    u += 0x7fffu + ((u >> 16) & 1u);   // RNE
    return (unsigned short)(u >> 16);
}

// async global->LDS, 16B per lane; LDS dest is wave-uniform base + lane*16
__device__ __forceinline__ void async_ld16(void* lds, const void* g) {
    __builtin_amdgcn_global_load_lds(
        (const __attribute__((address_space(1))) unsigned int*)g,
        (__attribute__((address_space(3))) unsigned int*)lds, 16, 0, 0);
}

// ---------------- kernel 1: convert weights fp32 -> bf16 ----------------
__global__ void k_cvt(const float* __restrict__ wq, const float* __restrict__ wp,
                      unsigned short* __restrict__ oq, unsigned short* __restrict__ op) {
    int i = blockIdx.x * 256 + threadIdx.x;
    if (i < 3 * CC * CC) oq[i] = f2bf(wq[i]);
    if (i < CC * CC)     op[i] = f2bf(wp[i]);
}

// ---------------- kernel 2: groupnorm stats (sum, sumsq) ----------------
__global__ void k_gnstats(const float* __restrict__ x, float* __restrict__ stats) {
    int blk = blockIdx.x;
    int b = blk >> 6, g = (blk >> 3) & 7, s = blk & 7;
    const float* p = x + ((size_t)(b * CC + g * GSZ)) * NN + s * 16384;
    int t = threadIdx.x;
    float s0 = 0.f, s1 = 0.f;
    #pragma unroll
    for (int i = 0; i < 64; ++i) { float v = p[i * 256 + t]; s0 += v; s1 += v * v; }
    #pragma unroll
    for (int m = 1; m <= 32; m <<= 1) { s0 += __shfl_xor(s0, m); s1 += __shfl_xor(s1, m); }
    __shared__ float ls[8];
    int w = t >> 6;
    if ((t & 63) == 0) { ls[w * 2] = s0; ls[w * 2 + 1] = s1; }
    __syncthreads();
    if (t == 0) {
        float a0 = ls[0] + ls[2] + ls[4] + ls[6];
        float a1 = ls[1] + ls[3] + ls[5] + ls[7];
        atomicAdd(&stats[(b * NG + g) * 2 + 0], a0);
        atomicAdd(&stats[(b * NG + g) * 2 + 1], a1);
    }
}

// ------- kernel 3: groupnorm apply + transpose -> ht[b][n][c] (bf16) -------
__global__ void k_gnapply(const float* __restrict__ x, const float* __restrict__ gw,
                          const float* __restrict__ gb, const float* __restrict__ stats,
                          unsigned short* __restrict__ ht) {
    int b = blockIdx.z, ct = blockIdx.y, nt = blockIdx.x;
    int c0 = ct * 32, n0 = nt * 64;
    int t = threadIdx.x;
    __shared__ float tile[32][65];
    const float* xp = x + ((size_t)(b * CC + c0)) * NN + n0;
    int cl = t >> 6, nl = t & 63;
    #pragma unroll
    for (int p = 0; p < 8; ++p)
        tile[p * 4 + cl][nl] = xp[(size_t)(p * 4 + cl) * NN + nl];
    float sum = stats[(b * NG + ct) * 2 + 0];
    float ssq = stats[(b * NG + ct) * 2 + 1];
    float mean = sum * (1.0f / 131072.0f);
    float var  = ssq * (1.0f / 131072.0f) - mean * mean;
    float inv  = rsqrtf(var + EPSV);
    __syncthreads();
    int nw = t >> 2, ci = (t & 3) * 8;
    alignas(16) unsigned short o8[8];
    #pragma unroll
    for (int j = 0; j < 8; ++j) {
        int c = c0 + ci + j;
        float v = (tile[ci + j][nw] - mean) * inv * gw[c] + gb[c];
        o8[j] = f2bf(v);
    }
    *reinterpret_cast<uint4*>(ht + ((size_t)(b * NN + n0 + nw)) * CC + c0 + ci) =
        *reinterpret_cast<const uint4*>(o8);
}

// ---------------- kernel 4: QKV GEMM (bf16 MFMA) ----------------
__global__ void k_qkv(const unsigned short* __restrict__ ht, const unsigned short* __restrict__ wq,
                      const float* __restrict__ qb,
                      unsigned short* __restrict__ qt, unsigned short* __restrict__ kt,
                      unsigned short* __restrict__ vt) {
    int b = blockIdx.z, by = blockIdx.y, bx = blockIdx.x;
    int t = threadIdx.x, wave = t >> 6, lane = t & 63;
    int l15 = lane & 15, quad = lane >> 4;
    int o0 = by * 16;
    int n = bx * 64 + wave * 16 + l15;
    const unsigned short* ap = wq + (size_t)(o0 + l15) * CC + quad * 8;
    const unsigned short* bp = ht + ((size_t)(b * NN + n)) * CC + quad * 8;
    f32x4 acc = {0.f, 0.f, 0.f, 0.f};
    #pragma unroll
    for (int kk = 0; kk < 8; ++kk) {
        bf16x8 a  = *reinterpret_cast<const bf16x8*>(ap + kk * 32);
        bf16x8 bb = *reinterpret_cast<const bf16x8*>(bp + kk * 32);
        acc = MFMA16(a, bb, acc);
    }
    int s = by >> 4, h = (by >> 2) & 3, d0 = (by & 3) * 16 + quad * 4;
    int orow = o0 + quad * 4;
    if (s == 0) {
        alignas(8) unsigned short o4[4];
        #pragma unroll
        for (int r = 0; r < 4; ++r) o4[r] = f2bf((acc[r] + qb[orow + r]) * SCALE);
        *reinterpret_cast<uint2*>(qt + (((size_t)(b * NH + h) * NN) + n) * HD + d0) =
            *reinterpret_cast<const uint2*>(o4);
    } else if (s == 1) {
        alignas(8) unsigned short o4[4];
        #pragma unroll
        for (int r = 0; r < 4; ++r) o4[r] = f2bf(acc[r] + qb[orow + r]);
        *reinterpret_cast<uint2*>(kt + (((size_t)(b * NH + h) * NN) + n) * HD + d0) =
            *reinterpret_cast<const uint2*>(o4);
    } else {
        #pragma unroll
        for (int r = 0; r < 4; ++r)
            vt[(((size_t)(b * NH + h) * HD) + d0 + r) * NN + n] = f2bf(acc[r] + qb[orow + r]);
    }
}

// ---------------- kernel 5: flash attention, LDS-staged K/V, double-buffered ----------------
// grid (64 q-tiles, B*NH); block 256 = 4 waves; wave owns 16 queries; key tile = 64.
// K tile [64 keys][64 d] and V^T tile [64 d][64 keys] staged via global_load_lds w=16,
// XOR-swizzled 16B chunks (slot = chunk ^ (row&7)) to break the 128B-row bank aliasing.
// Prefetch tile mt+1 issued before compute of tile mt; one __syncthreads per iter.
// S^T = MFMA(K,Q); P^T via 8 shfl + 4 v_perm; O^T = MFMA(V^T, P^T); unnormalized exp.
__global__ void __launch_bounds__(256, 4)
k_attn(const unsigned short* __restrict__ qt, const unsigned short* __restrict__ kt,
       const unsigned short* __restrict__ vt, unsigned short* __restrict__ ao) {
    int bh = blockIdx.y;
    int t = threadIdx.x, wave = t >> 6, lane = t & 63;
    int l15 = lane & 15, quad = lane >> 4;
    int qbase = blockIdx.x * 64 + wave * 16;
    const unsigned short* qp = qt + (size_t)bh * NN * HD;
    const unsigned short* kp = kt + (size_t)bh * NN * HD;
    const unsigned short* vp = vt + (size_t)bh * HD * NN;

    __shared__ alignas(16) unsigned char kbuf[2][8192];
    __shared__ alignas(16) unsigned char vbuf[2][8192];

    int lr = lane >> 3;          // row-within-8 for staging
    int lc = lane & 7;           // 16B slot for staging
    int swz = lc ^ lr;           // source chunk for slot lc of a row with row&7==lr

    // stage key tile [m0, m0+64) into buffer `buf`
    auto stage = [&](int m0, int buf) {
        const char* kc = (const char*)kp + (size_t)m0 * (HD * 2);
        #pragma unroll
        for (int j = 0; j < 2; ++j) {
            int krow = (wave * 2 + j) * 8 + lr;                      // 0..63
            async_ld16(&kbuf[buf][(wave * 2 + j) * 1024],
                       kc + (size_t)krow * 128 + swz * 16);
            int d = wave * 16 + j * 8 + lr;                          // 0..63
            async_ld16(&vbuf[buf][(wave * 16 + j * 8) * 128],
                       (const char*)vp + ((size_t)d * NN + m0) * 2 + swz * 16);
        }
    };

    stage(0, 0);

    bf16x8 qa0 = *reinterpret_cast<const bf16x8*>(qp + (size_t)(qbase + l15) * HD + quad * 8);
    bf16x8 qa1 = *reinterpret_cast<const bf16x8*>(qp + (size_t)(qbase + l15) * HD + 32 + quad * 8);

    f32x4 O[4];
    #pragma unroll
    for (int i = 0; i < 4; ++i) O[i] = (f32x4){0.f, 0.f, 0.f, 0.f};
    float li = 0.f;

    int srcA = (quad & 1) * 32 + l15;   // source lane for B-frag elems j=0..3
    int srcB = srcA + 16;               // j=4..7
    unsigned int psel = (quad >= 2) ? 0x07060302u : 0x05040100u;
    int sx = l15 & 7;                   // row&7 for all fragment rows below

    __syncthreads();

    for (int mt = 0; mt < 64; ++mt) {
        int cur = mt & 1;
        if (mt < 63) stage((mt + 1) * 64, cur ^ 1);

        const unsigned char* kb = kbuf[cur];
        const unsigned char* vbb = vbuf[cur];

        #pragma unroll
        for (int s = 0; s < 2; ++s) {
            int r0 = (s * 32 + l15) * 128;
            bf16x8 k00 = *reinterpret_cast<const bf16x8*>(kb + r0 + ((quad ^ sx) * 16));
            bf16x8 k01 = *reinterpret_cast<const bf16x8*>(kb + r0 + (((quad + 4) ^ sx) * 16));
            bf16x8 k10 = *reinterpret_cast<const bf16x8*>(kb + r0 + 2048 + ((quad ^ sx) * 16));
            bf16x8 k11 = *reinterpret_cast<const bf16x8*>(kb + r0 + 2048 + (((quad + 4) ^ sx) * 16));
            f32x4 s0 = {0.f, 0.f, 0.f, 0.f}, s1 = {0.f, 0.f, 0.f, 0.f};
            s0 = MFMA16(k00, qa0, s0);
            s0 = MFMA16(k01, qa1, s0);
            s1 = MFMA16(k10, qa0, s1);
            s1 = MFMA16(k11, qa1, s1);

            unsigned int pack[4];
            float psum = 0.f;
            #pragma unroll
            for (int r = 0; r < 4; ++r) {
                float p0 = __expf(fminf(s0[r], 80.f));
                float p1 = __expf(fminf(s1[r], 80.f));
                psum += p0 + p1;
                pack[r] = ((__float_as_uint(p0) + 0x8000u) >> 16) |
                          ((__float_as_uint(p1) + 0x8000u) & 0xffff0000u);
            }
            li += psum;

            int a0 = __shfl((int)pack[0], srcA);
            int a1 = __shfl((int)pack[1], srcA);
            int a2 = __shfl((int)pack[2], srcA);
            int a3 = __shfl((int)pack[3], srcA);
            int b0 = __shfl((int)pack[0], srcB);
            int b1 = __shfl((int)pack[1], srcB);
            int b2 = __shfl((int)pack[2], srcB);
            int b3 = __shfl((int)pack[3], srcB);
            alignas(16) unsigned int w[4];
            w[0] = __builtin_amdgcn_perm((unsigned)a1, (unsigned)a0, psel);
            w[1] = __builtin_amdgcn_perm((unsigned)a3, (unsigned)a2, psel);
            w[2] = __builtin_amdgcn_perm((unsigned)b1, (unsigned)b0, psel);
            w[3] = __builtin_amdgcn_perm((unsigned)b3, (unsigned)b2, psel);
            bf16x8 pfrag = *reinterpret_cast<const bf16x8*>(w);

            #pragma unroll
            for (int dc = 0; dc < 4; ++dc) {
                int d = dc * 16 + l15;
                bf16x8 vv = *reinterpret_cast<const bf16x8*>(
                    vbb + d * 128 + (((s * 4 + quad) ^ sx) * 16));
                O[dc] = MFMA16(vv, pfrag, O[dc]);   // O^T[d][q]
            }
        }
        __syncthreads();
    }

    li += __shfl_xor(li, 16);
    li += __shfl_xor(li, 32);
    float inv = 1.0f / li;

    int b = bh >> 2, h = bh & 3;
    int q = qbase + l15;
    #pragma unroll
    for (int dc = 0; dc < 4; ++dc) {
        alignas(8) unsigned short o4[4];
        #pragma unroll
        for (int r = 0; r < 4; ++r) o4[r] = f2bf(O[dc][r] * inv);
        *reinterpret_cast<uint2*>(ao + ((size_t)(b * NN) + q) * CC + h * HD + dc * 16 + quad * 4) =
            *reinterpret_cast<const uint2*>(o4);
    }
}

// ---------------- kernel 6: proj GEMM + bias + residual (fp32 out) ----------------
__global__ void k_proj(const unsigned short* __restrict__ ao, const unsigned short* __restrict__ wp,
                       const float* __restrict__ pb, const float* __restrict__ x,
                       float* __restrict__ out) {
    int b = blockIdx.z, by = blockIdx.y, bx = blockIdx.x;
    int t = threadIdx.x, wave = t >> 6, lane = t & 63;
    int l15 = lane & 15, quad = lane >> 4;
    int o0 = by * 16;
    int n = bx * 64 + wave * 16 + l15;
    const unsigned short* ap = wp + (size_t)(o0 + l15) * CC + quad * 8;
    const unsigned short* bp = ao + ((size_t)(b * NN + n)) * CC + quad * 8;
    f32x4 acc = {0.f, 0.f, 0.f, 0.f};
    #pragma unroll
    for (int kk = 0; kk < 8; ++kk) {
        bf16x8 a  = *reinterpret_cast<const bf16x8*>(ap + kk * 32);
        bf16x8 bb = *reinterpret_cast<const bf16x8*>(bp + kk * 32);
        acc = MFMA16(a, bb, acc);
    }
    #pragma unroll
    for (int r = 0; r < 4; ++r) {
        int o = o0 + quad * 4 + r;
        size_t idx = ((size_t)(b * CC + o)) * NN + n;
        out[idx] = acc[r] + pb[o] + x[idx];
    }
}

extern "C" void kernel_launch(void* const* d_in, const int* in_sizes, int n_in,
                              void* d_out, int out_size, void* d_ws, size_t ws_size,
                              hipStream_t stream) {
    const float* x     = (const float*)d_in[0];
    const float* gw    = (const float*)d_in[1];
    const float* gb    = (const float*)d_in[2];
    const float* qkvw  = (const float*)d_in[3];
    const float* qkvb  = (const float*)d_in[4];
    const float* projw = (const float*)d_in[5];
    const float* projb = (const float*)d_in[6];
    float* out = (float*)d_out;

    char* w = (char*)d_ws;
    size_t off = 0;
    unsigned short* ht = (unsigned short*)(w + off); off += (size_t)BB * NN * CC * 2;       // 8 MB
    unsigned short* qt = (unsigned short*)(w + off); off += (size_t)BB * NH * NN * HD * 2;  // 8 MB
    unsigned short* kt = (unsigned short*)(w + off); off += (size_t)BB * NH * NN * HD * 2;  // 8 MB
    unsigned short* vt = (unsigned short*)(w + off); off += (size_t)BB * NH * HD * NN * 2;  // 8 MB
    unsigned short* ao = (unsigned short*)(w + off); off += (size_t)BB * NN * CC * 2;       // 8 MB
    unsigned short* wqb = (unsigned short*)(w + off); off += (size_t)3 * CC * CC * 2;       // 384 KB
    unsigned short* wpb = (unsigned short*)(w + off); off += (size_t)CC * CC * 2;           // 128 KB
    float* stats = (float*)(w + off); off += BB * NG * 2 * sizeof(float);

    hipMemsetAsync(stats, 0, BB * NG * 2 * sizeof(float), stream);
    k_cvt<<<768, 256, 0, stream>>>(qkvw, projw, wqb, wpb);
    k_gnstats<<<BB * NG * 8, 256, 0, stream>>>(x, stats);
    k_gnapply<<<dim3(NN / 64, CC / 32, BB), 256, 0, stream>>>(x, gw, gb, stats, ht);
    k_qkv<<<dim3(NN / 64, 3 * CC / 16, BB), 256, 0, stream>>>(ht, wqb, qkvb, qt, kt, vt);
    k_attn<<<dim3(NN / 64, BB * NH), 256, 0, stream>>>(qt, kt, vt, ao);
    k_proj<<<dim3(NN / 64, CC / 16, BB), 256, 0, stream>>>(ao, wpb, projb, x, out);
}

// Round 5
// 240.866 us; speedup vs baseline: 2.7482x; 1.4471x over previous
//
#include <hip/hip_runtime.h>
#include <hip/hip_bf16.h>

// Problem constants (B=4, C=256, H=W=64, groups=8, heads=4)
#define BB   4
#define CC   256
#define NN   4096      // H*W
#define NH   4
#define HD   64
#define NG   8
#define GSZ  32        // channels per group
#define EPSV 1e-5f
#define SCALE_L2E 0.18033688f   // 64^-0.5 * log2(e), folded into q so softmax uses raw exp2

typedef __bf16 bf16x8 __attribute__((ext_vector_type(8)));
typedef float  f32x4  __attribute__((ext_vector_type(4)));

#define MFMA16(a, b, c) __builtin_amdgcn_mfma_f32_16x16x32_bf16((a), (b), (c), 0, 0, 0)

#if __has_builtin(__builtin_amdgcn_exp2f)
#define EXP2F __builtin_amdgcn_exp2f
#else
#define EXP2F exp2f
#endif

__device__ inline unsigned short f2bf(float f) {
    unsigned int u = __float_as_uint(f);
    u += 0x7fffu + ((u >> 16) & 1u);   // RNE
    return (unsigned short)(u >> 16);
}

// async global->LDS, 16B per lane; LDS dest is wave-uniform base + lane*16
__device__ __forceinline__ void async_ld16(void* lds, const void* g) {
    __builtin_amdgcn_global_load_lds(
        (const __attribute__((address_space(1))) unsigned int*)g,
        (__attribute__((address_space(3))) unsigned int*)lds, 16, 0, 0);
}

// ---------------- kernel 1: convert weights fp32 -> bf16 ----------------
__global__ void k_cvt(const float* __restrict__ wq, const float* __restrict__ wp,
                      unsigned short* __restrict__ oq, unsigned short* __restrict__ op) {
    int i = blockIdx.x * 256 + threadIdx.x;
    if (i < 3 * CC * CC) oq[i] = f2bf(wq[i]);
    if (i < CC * CC)     op[i] = f2bf(wp[i]);
}

// ---------------- kernel 2: groupnorm stats (sum, sumsq) ----------------
__global__ void k_gnstats(const float* __restrict__ x, float* __restrict__ stats) {
    int blk = blockIdx.x;
    int b = blk >> 6, g = (blk >> 3) & 7, s = blk & 7;
    const float* p = x + ((size_t)(b * CC + g * GSZ)) * NN + s * 16384;
    int t = threadIdx.x;
    float s0 = 0.f, s1 = 0.f;
    #pragma unroll
    for (int i = 0; i < 64; ++i) { float v = p[i * 256 + t]; s0 += v; s1 += v * v; }
    #pragma unroll
    for (int m = 1; m <= 32; m <<= 1) { s0 += __shfl_xor(s0, m); s1 += __shfl_xor(s1, m); }
    __shared__ float ls[8];
    int w = t >> 6;
    if ((t & 63) == 0) { ls[w * 2] = s0; ls[w * 2 + 1] = s1; }
    __syncthreads();
    if (t == 0) {
        float a0 = ls[0] + ls[2] + ls[4] + ls[6];
        float a1 = ls[1] + ls[3] + ls[5] + ls[7];
        atomicAdd(&stats[(b * NG + g) * 2 + 0], a0);
        atomicAdd(&stats[(b * NG + g) * 2 + 1], a1);
    }
}

// ------- kernel 3: groupnorm apply + transpose -> ht[b][n][c] (bf16) -------
__global__ void k_gnapply(const float* __restrict__ x, const float* __restrict__ gw,
                          const float* __restrict__ gb, const float* __restrict__ stats,
                          unsigned short* __restrict__ ht) {
    int b = blockIdx.z, ct = blockIdx.y, nt = blockIdx.x;
    int c0 = ct * 32, n0 = nt * 64;
    int t = threadIdx.x;
    __shared__ float tile[32][65];
    const float* xp = x + ((size_t)(b * CC + c0)) * NN + n0;
    int cl = t >> 6, nl = t & 63;
    #pragma unroll
    for (int p = 0; p < 8; ++p)
        tile[p * 4 + cl][nl] = xp[(size_t)(p * 4 + cl) * NN + nl];
    float sum = stats[(b * NG + ct) * 2 + 0];
    float ssq = stats[(b * NG + ct) * 2 + 1];
    float mean = sum * (1.0f / 131072.0f);
    float var  = ssq * (1.0f / 131072.0f) - mean * mean;
    float inv  = rsqrtf(var + EPSV);
    __syncthreads();
    int nw = t >> 2, ci = (t & 3) * 8;
    alignas(16) unsigned short o8[8];
    #pragma unroll
    for (int j = 0; j < 8; ++j) {
        int c = c0 + ci + j;
        float v = (tile[ci + j][nw] - mean) * inv * gw[c] + gb[c];
        o8[j] = f2bf(v);
    }
    *reinterpret_cast<uint4*>(ht + ((size_t)(b * NN + n0 + nw)) * CC + c0 + ci) =
        *reinterpret_cast<const uint4*>(o8);
}

// ---------------- kernel 4: QKV GEMM, 128x128 tile, double-buffered LDS ----------------
// C[o][nn] = sum_c W[o][c] * ht[nn][c];  o=by*128.., nn=bx*128.. (nn = b*4096+n).
// Epilogue: s=o>>8 selects q (scale*log2e + bias, [bh][n][d]) / k (bias, [bh][n][d])
// / v (bias, [bh][d][n]).
__global__ void __launch_bounds__(256)
k_qkv(const unsigned short* __restrict__ ht, const unsigned short* __restrict__ wq,
      const float* __restrict__ qb,
      unsigned short* __restrict__ qt, unsigned short* __restrict__ kt,
      unsigned short* __restrict__ vt) {
    int bx = blockIdx.x, by = blockIdx.y;
    int t = threadIdx.x, wave = t >> 6, lane = t & 63;
    int l15 = lane & 15, quad = lane >> 4;
    int wm = wave >> 1, wn = wave & 1;

    __shared__ alignas(16) unsigned char At[2][8192];   // [128 rows][32 c] bf16, 64B rows
    __shared__ alignas(16) unsigned char Bt[2][8192];

    const char* Ag = (const char*)wq + (size_t)by * 65536;
    const char* Bg = (const char*)ht + (size_t)bx * 65536;
    int row0 = t >> 2, slot = t & 3;                    // chunk t
    size_t a0 = (size_t)row0 * 512 + slot * 16;
    size_t a1 = a0 + 64 * 512;                          // chunk t+256
    unsigned int dst0 = wave * 1024;                    // lane*16 added by HW

    auto stage = [&](int buf, int kk) {
        size_t ko = (size_t)kk * 64;
        async_ld16(At[buf] + dst0,        Ag + a0 + ko);
        async_ld16(At[buf] + 4096 + dst0, Ag + a1 + ko);
        async_ld16(Bt[buf] + dst0,        Bg + a0 + ko);
        async_ld16(Bt[buf] + 4096 + dst0, Bg + a1 + ko);
    };

    f32x4 acc[4][4];
    #pragma unroll
    for (int i = 0; i < 4; ++i)
        #pragma unroll
        for (int j = 0; j < 4; ++j) acc[i][j] = (f32x4){0.f, 0.f, 0.f, 0.f};

    stage(0, 0);
    __syncthreads();

    for (int kk = 0; kk < 8; ++kk) {
        int cur = kk & 1;
        if (kk < 7) stage(cur ^ 1, kk + 1);
        bf16x8 af[4], bf[4];
        #pragma unroll
        for (int f = 0; f < 4; ++f) {
            af[f] = *reinterpret_cast<const bf16x8*>(At[cur] + (wm * 64 + f * 16 + l15) * 64 + quad * 16);
            bf[f] = *reinterpret_cast<const bf16x8*>(Bt[cur] + (wn * 64 + f * 16 + l15) * 64 + quad * 16);
        }
        #pragma unroll
        for (int fm = 0; fm < 4; ++fm)
            #pragma unroll
            for (int fn = 0; fn < 4; ++fn)
                acc[fm][fn] = MFMA16(af[fm], bf[fn], acc[fm][fn]);
        __syncthreads();
    }

    int s = by >> 1;
    int nn0 = bx * 128;
    int b = nn0 >> 12, nbase = nn0 & 4095;
    #pragma unroll
    for (int fm = 0; fm < 4; ++fm) {
        int o = by * 128 + wm * 64 + fm * 16 + quad * 4;
        int h = (o >> 6) & 3, d0 = o & 63;
        float bias[4];
        #pragma unroll
        for (int r = 0; r < 4; ++r) bias[r] = qb[o + r];
        #pragma unroll
        for (int fn = 0; fn < 4; ++fn) {
            int n = nbase + wn * 64 + fn * 16 + l15;
            if (s == 0) {
                alignas(8) unsigned short o4[4];
                #pragma unroll
                for (int r = 0; r < 4; ++r) o4[r] = f2bf((acc[fm][fn][r] + bias[r]) * SCALE_L2E);
                *reinterpret_cast<uint2*>(qt + (((size_t)(b * NH + h) * NN) + n) * HD + d0) =
                    *reinterpret_cast<const uint2*>(o4);
            } else if (s == 1) {
                alignas(8) unsigned short o4[4];
                #pragma unroll
                for (int r = 0; r < 4; ++r) o4[r] = f2bf(acc[fm][fn][r] + bias[r]);
                *reinterpret_cast<uint2*>(kt + (((size_t)(b * NH + h) * NN) + n) * HD + d0) =
                    *reinterpret_cast<const uint2*>(o4);
            } else {
                #pragma unroll
                for (int r = 0; r < 4; ++r)
                    vt[((size_t)(b * NH + h) * HD + d0 + r) * NN + n] = f2bf(acc[fm][fn][r] + bias[r]);
            }
        }
    }
}

// ---------------- kernel 5: flash attention, 8-wave blocks, LDS K/V double-buffered ----------------
// grid (32 q-tiles of 128, B*NH); block 512 = 8 waves; wave owns 16 queries; key tile 64.
// K tile [64 keys][64 d], V^T tile [64 d][64 keys] staged via global_load_lds w=16 with
// XOR-swizzled 16B chunks (slot = chunk ^ (row&7)). Unnormalized exp2 (log2e folded in q).
__global__ void __launch_bounds__(512, 4)
k_attn(const unsigned short* __restrict__ qt, const unsigned short* __restrict__ kt,
       const unsigned short* __restrict__ vt, unsigned short* __restrict__ ao) {
    int bh = blockIdx.y;
    int t = threadIdx.x, wave = t >> 6, lane = t & 63;
    int l15 = lane & 15, quad = lane >> 4;
    int qbase = blockIdx.x * 128 + wave * 16;
    const unsigned short* qp = qt + (size_t)bh * NN * HD;
    const unsigned short* kp = kt + (size_t)bh * NN * HD;
    const unsigned short* vp = vt + (size_t)bh * HD * NN;

    __shared__ alignas(16) unsigned char kbuf[2][8192];
    __shared__ alignas(16) unsigned char vbuf[2][8192];

    int lr = lane >> 3;          // row-within-8 for staging
    int lc = lane & 7;           // 16B slot
    int swz = lc ^ lr;

    // per-lane staging sources (advanced by increments each tile)
    const char* ksrc = (const char*)kp + (size_t)(wave * 8 + lr) * 128 + swz * 16;
    const char* vsrc = (const char*)vp + (size_t)(wave * 8 + lr) * 8192 + swz * 16;
    unsigned int kdst = wave * 1024;   // + lane*16 by HW

    // stage tile 0 into buffer 0
    async_ld16(kbuf[0] + kdst, ksrc);
    async_ld16(vbuf[0] + kdst, vsrc);

    bf16x8 qa0 = *reinterpret_cast<const bf16x8*>(qp + (size_t)(qbase + l15) * HD + quad * 8);
    bf16x8 qa1 = *reinterpret_cast<const bf16x8*>(qp + (size_t)(qbase + l15) * HD + 32 + quad * 8);

    f32x4 O[4];
    #pragma unroll
    for (int i = 0; i < 4; ++i) O[i] = (f32x4){0.f, 0.f, 0.f, 0.f};
    float li = 0.f;

    int srcA = (quad & 1) * 32 + l15;   // source lane for B-frag elems j=0..3
    int srcB = srcA + 16;               // j=4..7
    unsigned int psel = (quad >= 2) ? 0x07060302u : 0x05040100u;
    int sx = l15 & 7;                   // row&7 for all fragment rows used below

    __syncthreads();

    for (int mt = 0; mt < 64; ++mt) {
        int cur = mt & 1;
        if (mt < 63) {
            ksrc += 8192; vsrc += 128;
            async_ld16(kbuf[cur ^ 1] + kdst, ksrc);
            async_ld16(vbuf[cur ^ 1] + kdst, vsrc);
        }

        const unsigned char* kb  = kbuf[cur];
        const unsigned char* vbb = vbuf[cur];

        #pragma unroll
        for (int s = 0; s < 2; ++s) {
            int r0 = (s * 32 + l15) * 128;
            bf16x8 k00 = *reinterpret_cast<const bf16x8*>(kb + r0 + ((quad ^ sx) * 16));
            bf16x8 k01 = *reinterpret_cast<const bf16x8*>(kb + r0 + (((quad + 4) ^ sx) * 16));
            bf16x8 k10 = *reinterpret_cast<const bf16x8*>(kb + r0 + 2048 + ((quad ^ sx) * 16));
            bf16x8 k11 = *reinterpret_cast<const bf16x8*>(kb + r0 + 2048 + (((quad + 4) ^ sx) * 16));
            f32x4 s0 = {0.f, 0.f, 0.f, 0.f}, s1 = {0.f, 0.f, 0.f, 0.f};
            s0 = MFMA16(k00, qa0, s0);
            s0 = MFMA16(k01, qa1, s0);
            s1 = MFMA16(k10, qa0, s1);
            s1 = MFMA16(k11, qa1, s1);

            unsigned int pack[4];
            float psum = 0.f;
            #pragma unroll
            for (int r = 0; r < 4; ++r) {
                float p0 = EXP2F(fminf(s0[r], 115.f));
                float p1 = EXP2F(fminf(s1[r], 115.f));
                psum += p0 + p1;
                pack[r] = ((__float_as_uint(p0) + 0x8000u) >> 16) |
                          ((__float_as_uint(p1) + 0x8000u) & 0xffff0000u);
            }
            li += psum;

            int a0 = __shfl((int)pack[0], srcA);
            int a1 = __shfl((int)pack[1], srcA);
            int a2 = __shfl((int)pack[2], srcA);
            int a3 = __shfl((int)pack[3], srcA);
            int b0 = __shfl((int)pack[0], srcB);
            int b1 = __shfl((int)pack[1], srcB);
            int b2 = __shfl((int)pack[2], srcB);
            int b3 = __shfl((int)pack[3], srcB);
            alignas(16) unsigned int w[4];
            w[0] = __builtin_amdgcn_perm((unsigned)a1, (unsigned)a0, psel);
            w[1] = __builtin_amdgcn_perm((unsigned)a3, (unsigned)a2, psel);
            w[2] = __builtin_amdgcn_perm((unsigned)b1, (unsigned)b0, psel);
            w[3] = __builtin_amdgcn_perm((unsigned)b3, (unsigned)b2, psel);
            bf16x8 pfrag = *reinterpret_cast<const bf16x8*>(w);

            #pragma unroll
            for (int dc = 0; dc < 4; ++dc) {
                int d = dc * 16 + l15;
                bf16x8 vv = *reinterpret_cast<const bf16x8*>(
                    vbb + d * 128 + (((s * 4 + quad) ^ sx) * 16));
                O[dc] = MFMA16(vv, pfrag, O[dc]);   // O^T[d][q]
            }
        }
        __syncthreads();
    }

    li += __shfl_xor(li, 16);
    li += __shfl_xor(li, 32);
    float inv = 1.0f / li;

    int b = bh >> 2, h = bh & 3;
    int q = qbase + l15;
    #pragma unroll
    for (int dc = 0; dc < 4; ++dc) {
        alignas(8) unsigned short o4[4];
        #pragma unroll
        for (int r = 0; r < 4; ++r) o4[r] = f2bf(O[dc][r] * inv);
        *reinterpret_cast<uint2*>(ao + ((size_t)(b * NN) + q) * CC + h * HD + dc * 16 + quad * 4) =
            *reinterpret_cast<const uint2*>(o4);
    }
}

// ---------------- kernel 6: proj GEMM 64x128 tile + bias + residual (fp32 out) ----------------
__global__ void __launch_bounds__(256)
k_proj(const unsigned short* __restrict__ ao, const unsigned short* __restrict__ wp,
       const float* __restrict__ pb, const float* __restrict__ x,
       float* __restrict__ out) {
    int bx = blockIdx.x, by = blockIdx.y;
    int t = threadIdx.x, wave = t >> 6, lane = t & 63;
    int l15 = lane & 15, quad = lane >> 4;
    int wm = wave >> 1, wn = wave & 1;

    __shared__ alignas(16) unsigned char At[2][4096];   // [64 rows][32 c]
    __shared__ alignas(16) unsigned char Bt[2][8192];   // [128 rows][32 c]

    const char* Ag = (const char*)wp + (size_t)by * 32768;
    const char* Bg = (const char*)ao + (size_t)bx * 65536;
    int row0 = t >> 2, slot = t & 3;
    size_t a0 = (size_t)row0 * 512 + slot * 16;
    size_t a1 = a0 + 64 * 512;
    unsigned int dst0 = wave * 1024;

    auto stage = [&](int buf, int kk) {
        size_t ko = (size_t)kk * 64;
        async_ld16(At[buf] + dst0,        Ag + a0 + ko);
        async_ld16(Bt[buf] + dst0,        Bg + a0 + ko);
        async_ld16(Bt[buf] + 4096 + dst0, Bg + a1 + ko);
    };

    f32x4 acc[2][4];
    #pragma unroll
    for (int i = 0; i < 2; ++i)
        #pragma unroll
        for (int j = 0; j < 4; ++j) acc[i][j] = (f32x4){0.f, 0.f, 0.f, 0.f};

    stage(0, 0);
    __syncthreads();

    for (int kk = 0; kk < 8; ++kk) {
        int cur = kk & 1;
        if (kk < 7) stage(cur ^ 1, kk + 1);
        bf16x8 af[2], bf[4];
        #pragma unroll
        for (int f = 0; f < 2; ++f)
            af[f] = *reinterpret_cast<const bf16x8*>(At[cur] + (wm * 32 + f * 16 + l15) * 64 + quad * 16);
        #pragma unroll
        for (int f = 0; f < 4; ++f)
            bf[f] = *reinterpret_cast<const bf16x8*>(Bt[cur] + (wn * 64 + f * 16 + l15) * 64 + quad * 16);
        #pragma unroll
        for (int fm = 0; fm < 2; ++fm)
            #pragma unroll
            for (int fn = 0; fn < 4; ++fn)
                acc[fm][fn] = MFMA16(af[fm], bf[fn], acc[fm][fn]);
        __syncthreads();
    }

    int nn0 = bx * 128;
    int b = nn0 >> 12, nbase = nn0 & 4095;
    #pragma unroll
    for (int fm = 0; fm < 2; ++fm) {
        int o = by * 64 + wm * 32 + fm * 16 + quad * 4;
        float bias[4];
        #pragma unroll
        for (int r = 0; r < 4; ++r) bias[r] = pb[o + r];
        #pragma unroll
        for (int fn = 0; fn < 4; ++fn) {
            int n = nbase + wn * 64 + fn * 16 + l15;
            #pragma unroll
            for (int r = 0; r < 4; ++r) {
                size_t idx = ((size_t)(b * CC + o + r)) * NN + n;
                out[idx] = acc[fm][fn][r] + bias[r] + x[idx];
            }
        }
    }
}

extern "C" void kernel_launch(void* const* d_in, const int* in_sizes, int n_in,
                              void* d_out, int out_size, void* d_ws, size_t ws_size,
                              hipStream_t stream) {
    const float* x     = (const float*)d_in[0];
    const float* gw    = (const float*)d_in[1];
    const float* gb    = (const float*)d_in[2];
    const float* qkvw  = (const float*)d_in[3];
    const float* qkvb  = (const float*)d_in[4];
    const float* projw = (const float*)d_in[5];
    const float* projb = (const float*)d_in[6];
    float* out = (float*)d_out;

    char* w = (char*)d_ws;
    size_t off = 0;
    unsigned short* ht = (unsigned short*)(w + off); off += (size_t)BB * NN * CC * 2;       // 8 MB
    unsigned short* qt = (unsigned short*)(w + off); off += (size_t)BB * NH * NN * HD * 2;  // 8 MB
    unsigned short* kt = (unsigned short*)(w + off); off += (size_t)BB * NH * NN * HD * 2;  // 8 MB
    unsigned short* vt = (unsigned short*)(w + off); off += (size_t)BB * NH * HD * NN * 2;  // 8 MB
    unsigned short* ao = (unsigned short*)(w + off); off += (size_t)BB * NN * CC * 2;       // 8 MB
    unsigned short* wqb = (unsigned short*)(w + off); off += (size_t)3 * CC * CC * 2;       // 384 KB
    unsigned short* wpb = (unsigned short*)(w + off); off += (size_t)CC * CC * 2;           // 128 KB
    float* stats = (float*)(w + off); off += BB * NG * 2 * sizeof(float);

    hipMemsetAsync(stats, 0, BB * NG * 2 * sizeof(float), stream);
    k_cvt<<<768, 256, 0, stream>>>(qkvw, projw, wqb, wpb);
    k_gnstats<<<BB * NG * 8, 256, 0, stream>>>(x, stats);
    k_gnapply<<<dim3(NN / 64, CC / 32, BB), 256, 0, stream>>>(x, gw, gb, stats, ht);
    k_qkv<<<dim3(BB * NN / 128, 6), 256, 0, stream>>>(ht, wqb, qkvb, qt, kt, vt);
    k_attn<<<dim3(NN / 128, BB * NH), 512, 0, stream>>>(qt, kt, vt, ao);
    k_proj<<<dim3(BB * NN / 128, CC / 64), 256, 0, stream>>>(ao, wpb, projb, x, out);  // by: 4x64 = 256 ch
}